// Round 1
// 498.894 us; speedup vs baseline: 1.0742x; 1.0742x over previous
//
#include <hip/hip_runtime.h>
#include <math.h>

#define SCAN_B 512

typedef _Float16 half4v __attribute__((ext_vector_type(4)));

__device__ __forceinline__ float leaky02(float x){ return x > 0.f ? x : 0.2f * x; }
__device__ __forceinline__ float eluf(float x){ return x > 0.f ? x : expm1f(x); }

// ---------------- GEMM1: h1 = x @ W1  (N x 128) @ (128 x 128), fused alpha dots ----
// h1 stored as fp16 (feeds only the gather); alpha dots computed from f32 acc.
__global__ __launch_bounds__(128) void gemm1_kernel(
    const float* __restrict__ x, const float* __restrict__ W,
    const float* __restrict__ a_src, const float* __restrict__ a_dst, // flat [128]
    _Float16* __restrict__ h, float* __restrict__ as_, float* __restrict__ ad_, int n)
{
  const int t = threadIdx.x;
  const int row0 = blockIdx.x * 8;
  __shared__ float xs[8][128];
  __shared__ float sS[8][128];
  __shared__ float sD[8][128];
  for (int idx = t; idx < 8 * 32; idx += 128) {
    int r = idx >> 5, k4 = idx & 31;
    float4 v = (row0 + r < n) ? ((const float4*)x)[(size_t)(row0 + r) * 32 + k4]
                              : make_float4(0.f, 0.f, 0.f, 0.f);
    *(float4*)&xs[r][k4 * 4] = v;
  }
  __syncthreads();
  float acc[8] = {0,0,0,0,0,0,0,0};
  for (int k = 0; k < 128; k += 4) {
    float w0 = W[(k + 0) * 128 + t];
    float w1 = W[(k + 1) * 128 + t];
    float w2 = W[(k + 2) * 128 + t];
    float w3 = W[(k + 3) * 128 + t];
    #pragma unroll
    for (int r = 0; r < 8; ++r) {
      float4 xv = *(const float4*)&xs[r][k];
      acc[r] += xv.x * w0 + xv.y * w1 + xv.z * w2 + xv.w * w3;
    }
  }
  float asv = a_src[t], adv = a_dst[t];
  #pragma unroll
  for (int r = 0; r < 8; ++r) {
    float hv = acc[r];
    if (row0 + r < n) h[(size_t)(row0 + r) * 128 + t] = (_Float16)hv;
    sS[r][t] = hv * asv;
    sD[r][t] = hv * adv;
  }
  __syncthreads();
  if (t < 64) {
    int r = t >> 3, head = t & 3, which = (t >> 2) & 1;
    if (row0 + r < n) {
      const float (*buf)[128] = which ? sD : sS;
      double s = 0;
      for (int cc = 0; cc < 32; ++cc) s += (double)buf[r][head * 32 + cc];
      float* dstp = which ? ad_ : as_;
      dstp[(row0 + r) * 4 + head] = (float)s;
    }
  }
}

// ---------------- GEMM2: h2 = act1 @ W2 (N x 128) @ (128 x 32), fused alpha dots ---
__global__ __launch_bounds__(128) void gemm2_kernel(
    const float* __restrict__ x, const float* __restrict__ W,
    const float* __restrict__ a_src, const float* __restrict__ a_dst, // [32]
    _Float16* __restrict__ h, float* __restrict__ as_, float* __restrict__ ad_, int n)
{
  const int t = threadIdx.x;
  const int row0 = blockIdx.x * 8;
  __shared__ float xs[8][128];
  __shared__ float sH[8][32];
  for (int idx = t; idx < 8 * 32; idx += 128) {
    int r = idx >> 5, k4 = idx & 31;
    float4 v = (row0 + r < n) ? ((const float4*)x)[(size_t)(row0 + r) * 32 + k4]
                              : make_float4(0.f, 0.f, 0.f, 0.f);
    *(float4*)&xs[r][k4 * 4] = v;
  }
  __syncthreads();
  int col = t & 31, rp = t >> 5;
  int r0 = rp * 2, r1 = r0 + 1;
  float a0 = 0, a1 = 0;
  for (int k = 0; k < 128; k += 4) {
    float w0 = W[(k + 0) * 32 + col];
    float w1 = W[(k + 1) * 32 + col];
    float w2 = W[(k + 2) * 32 + col];
    float w3 = W[(k + 3) * 32 + col];
    float4 x0 = *(const float4*)&xs[r0][k];
    float4 x1 = *(const float4*)&xs[r1][k];
    a0 += x0.x * w0 + x0.y * w1 + x0.z * w2 + x0.w * w3;
    a1 += x1.x * w0 + x1.y * w1 + x1.z * w2 + x1.w * w3;
  }
  if (row0 + r0 < n) h[(size_t)(row0 + r0) * 32 + col] = (_Float16)a0;
  if (row0 + r1 < n) h[(size_t)(row0 + r1) * 32 + col] = (_Float16)a1;
  sH[r0][col] = a0; sH[r1][col] = a1;
  __syncthreads();
  if (t < 16) {
    int r = t >> 1, which = t & 1;
    if (row0 + r < n) {
      const float* a = which ? a_dst : a_src;
      double s = 0;
      for (int cc = 0; cc < 32; ++cc) s += (double)sH[r][cc] * (double)a[cc];
      (which ? ad_ : as_)[row0 + r] = (float)s;
    }
  }
}

// ---------------- CSR build ---------------------------------------------------------
__global__ void degree_kernel(const int* __restrict__ dst, int* __restrict__ deg, int E) {
  int e = blockIdx.x * blockDim.x + threadIdx.x;
  if (e < E) atomicAdd(&deg[dst[e]], 1);
}

__global__ __launch_bounds__(SCAN_B) void scan_partial_kernel(
    const int* __restrict__ deg, int* __restrict__ partial, int n)
{
  __shared__ int s[SCAN_B];
  int i = blockIdx.x * SCAN_B + threadIdx.x;
  s[threadIdx.x] = (i < n) ? deg[i] : 0;
  __syncthreads();
  for (int off = SCAN_B / 2; off > 0; off >>= 1) {
    if (threadIdx.x < off) s[threadIdx.x] += s[threadIdx.x + off];
    __syncthreads();
  }
  if (threadIdx.x == 0) partial[blockIdx.x] = s[0];
}

// single-block parallel exclusive scan over the per-block partials
__global__ __launch_bounds__(256) void scan_offsets_kernel(int* __restrict__ partial, int nb) {
  __shared__ int s[256];
  __shared__ int carry_s;
  int t = threadIdx.x;
  if (t == 0) carry_s = 0;
  __syncthreads();
  for (int b = 0; b < nb; b += 256) {
    int v = (b + t < nb) ? partial[b + t] : 0;
    s[t] = v;
    __syncthreads();
    for (int off = 1; off < 256; off <<= 1) {
      int x = (t >= off) ? s[t - off] : 0;
      __syncthreads();
      s[t] += x;
      __syncthreads();
    }
    int incl = s[t];
    int carry = carry_s;
    if (b + t < nb) partial[b + t] = carry + incl - v;   // exclusive
    __syncthreads();
    if (t == 255) carry_s = carry + incl;
    __syncthreads();
  }
}

__global__ __launch_bounds__(SCAN_B) void scan_final_kernel(
    const int* __restrict__ deg, const int* __restrict__ partial,
    int* __restrict__ rowStart, int n, int Etot)
{
  __shared__ int s[SCAN_B];
  int i = blockIdx.x * SCAN_B + threadIdx.x;
  int v = (i < n) ? deg[i] : 0;
  s[threadIdx.x] = v;
  __syncthreads();
  for (int off = 1; off < SCAN_B; off <<= 1) {
    int xv = (threadIdx.x >= off) ? s[threadIdx.x - off] : 0;
    __syncthreads();
    s[threadIdx.x] += xv;
    __syncthreads();
  }
  if (i < n) rowStart[i] = partial[blockIdx.x] + s[threadIdx.x] - v;  // exclusive scan
  if (i == 0) rowStart[n] = Etot;
}

__global__ void fill_kernel(const int* __restrict__ src, const int* __restrict__ dst,
    const int* __restrict__ rowStart, int* __restrict__ cursor,
    int* __restrict__ col, int E)
{
  int e = blockIdx.x * blockDim.x + threadIdx.x;
  if (e < E) {
    int d = dst[e];
    int pos = rowStart[d] + atomicAdd(&cursor[d], 1);
    col[pos] = src[e];
  }
}

// ---------------- GAT aggregation v4: wave-private, barrier-free, fp16 features -----
// Each node owned by L = CTOT/4 lanes of one wave. Staging in wave-private LDS
// (no __syncthreads). Every lane accumulates the full denominator for its head.
// Features gathered as fp16 (half the bytes of v3); accumulation f32/f64.
template<int CTOT, int H>
__global__ __launch_bounds__(256) void gat_aggr3_kernel(
    const _Float16* __restrict__ feat,  // [n, CTOT] fp16
    const float* __restrict__ as_,      // [n, H]
    const float* __restrict__ ad_,      // [n, H]
    const int* __restrict__ rowStart,
    const int* __restrict__ col,
    const float* __restrict__ bias,     // [CTOT]
    float* __restrict__ out, int n)
{
  constexpr int L    = CTOT / 4;   // lanes per node
  constexpr int NPW  = 64 / L;     // nodes per wave
  constexpr int NPB  = 4 * NPW;    // nodes per block (256 thr = 4 waves)
  constexpr int CH   = CTOT / H;   // channels per head
  constexpr int CHUNK = L;         // edges staged per round

  const int t    = threadIdx.x;
  const int wave = t >> 6;
  const int lane = t & 63;
  const int grp  = lane / L;
  const int li   = lane % L;
  const int slot = wave * NPW + grp;
  const int node = blockIdx.x * NPB + slot;
  const int hc   = (4 * li) / CH;

  __shared__ int   s_off[NPB][CHUNK + 1];
  __shared__ float s_p[NPB][CHUNK * H + 1];

  if (node >= n) return;   // safe: no barriers below

  const int beg = rowStart[node];
  const int deg = rowStart[node + 1] - beg;

  float adv[H], eself[H];
  #pragma unroll
  for (int h = 0; h < H; ++h) adv[h] = ad_[node * H + h];
  #pragma unroll
  for (int h = 0; h < H; ++h) eself[h] = leaky02(as_[node * H + h] + adv[h]);

  float es = 0.f;
  #pragma unroll
  for (int h = 0; h < H; ++h) if (h == hc) es = eself[h];
  const float ps = expf(es);

  const half4v fself = *(const half4v*)(feat + (size_t)node * CTOT + 4 * li);
  double acc64[4];
  acc64[0] = (double)ps * (double)(float)fself.x;
  acc64[1] = (double)ps * (double)(float)fself.y;
  acc64[2] = (double)ps * (double)(float)fself.z;
  acc64[3] = (double)ps * (double)(float)fself.w;
  double den64 = (double)ps;

  for (int base = 0; base < deg; base += CHUNK) {
    const int cnt = min(CHUNK, deg - base);
    if (li < cnt) {
      int s = col[beg + base + li];
      s_off[slot][li] = s * CTOT;
      if constexpr (H == 4) {
        float4 q = ((const float4*)as_)[s];
        s_p[slot][li * 4 + 0] = expf(leaky02(q.x + adv[0]));
        s_p[slot][li * 4 + 1] = expf(leaky02(q.y + adv[1]));
        s_p[slot][li * 4 + 2] = expf(leaky02(q.z + adv[2]));
        s_p[slot][li * 4 + 3] = expf(leaky02(q.w + adv[3]));
      } else {
        s_p[slot][li] = expf(leaky02(as_[s] + adv[0]));
      }
    }
    __builtin_amdgcn_wave_barrier();   // keep staging before consumption
    float a0 = 0.f, a1 = 0.f, a2 = 0.f, a3 = 0.f, df = 0.f;
    #pragma unroll 8
    for (int j = 0; j < cnt; ++j) {
      int off = s_off[slot][j];
      float p = (H == 4) ? s_p[slot][j * 4 + hc] : s_p[slot][j];
      const half4v f = *(const half4v*)(feat + off + 4 * li);
      a0 += p * (float)f.x; a1 += p * (float)f.y;
      a2 += p * (float)f.z; a3 += p * (float)f.w;
      df += p;
    }
    __builtin_amdgcn_wave_barrier();   // keep consumption before next staging
    acc64[0] += a0; acc64[1] += a1; acc64[2] += a2; acc64[3] += a3;
    den64 += df;
  }

  const float4 bv = *(const float4*)(bias + 4 * li);
  float4 o;
  o.x = eluf((float)(acc64[0] / den64) + bv.x);
  o.y = eluf((float)(acc64[1] / den64) + bv.y);
  o.z = eluf((float)(acc64[2] / den64) + bv.z);
  o.w = eluf((float)(acc64[3] / den64) + bv.w);
  *(float4*)(out + (size_t)node * CTOT + 4 * li) = o;
}

// ---------------- pooling (batch is sorted: run-length flush) -----------------------
__global__ __launch_bounds__(256) void pool_kernel(const float* __restrict__ act2,
    const int* __restrict__ batch, float* __restrict__ pooled,
    float* __restrict__ cnt, int n)
{
  int t = threadIdx.x;
  int c = t & 31, r = t >> 5;
  int n0 = blockIdx.x * 64 + r * 8;
  float run = 0.f; int gcur = -1; int len = 0;
  for (int i = 0; i < 8; ++i) {
    int nd = n0 + i;
    if (nd >= n) break;
    int gb = batch[nd];
    if (gb != gcur) {
      if (gcur >= 0) {
        atomicAdd(&pooled[gcur * 32 + c], run);
        if (c == 0) atomicAdd(&cnt[gcur], (float)len);
      }
      gcur = gb; run = 0.f; len = 0;
    }
    run += act2[(size_t)nd * 32 + c];
    len++;
  }
  if (gcur >= 0) {
    atomicAdd(&pooled[gcur * 32 + c], run);
    if (c == 0) atomicAdd(&cnt[gcur], (float)len);
  }
}

__global__ void classifier_kernel(const float* __restrict__ pooled, const float* __restrict__ cnt,
    const float* __restrict__ Wc1, const float* __restrict__ bc1,
    const float* __restrict__ Wc2, const float* __restrict__ bc2,
    float* __restrict__ outp, int g_total)
{
  int g = blockIdx.x * blockDim.x + threadIdx.x;
  if (g < g_total) {
    float inv = 1.0f / cnt[g];
    float pm[32];
    for (int c = 0; c < 32; ++c) pm[c] = pooled[g * 32 + c] * inv;
    double o = (double)bc2[0];
    for (int j = 0; j < 16; ++j) {
      double z = (double)bc1[j];
      for (int c = 0; c < 32; ++c) z += (double)pm[c] * (double)Wc1[c * 16 + j];
      float zr = (float)z;
      zr = zr > 0.f ? zr : 0.f;
      o += (double)zr * (double)Wc2[j];
    }
    outp[g] = (float)o;
  }
}

// ---------------- launch ------------------------------------------------------------
extern "C" void kernel_launch(void* const* d_in, const int* in_sizes, int n_in,
                              void* d_out, int out_size, void* d_ws, size_t ws_size,
                              hipStream_t stream)
{
  const float* x      = (const float*)d_in[0];
  const int*   ei     = (const int*)d_in[1];
  const int*   batch  = (const int*)d_in[3];
  const float* W1     = (const float*)d_in[4];
  const float* a_src1 = (const float*)d_in[5];
  const float* a_dst1 = (const float*)d_in[6];
  const float* b1     = (const float*)d_in[7];
  const float* W2     = (const float*)d_in[8];
  const float* a_src2 = (const float*)d_in[9];
  const float* a_dst2 = (const float*)d_in[10];
  const float* b2     = (const float*)d_in[11];
  const float* Wc1    = (const float*)d_in[12];
  const float* bc1    = (const float*)d_in[13];
  const float* Wc2    = (const float*)d_in[14];
  const float* bc2    = (const float*)d_in[15];

  const int N = in_sizes[0] / 128;
  const int E = in_sizes[1] / 2;
  const int G = out_size;

  const int* srcv = ei;
  const int* dstv = ei + E;

  char* ws = (char*)d_ws;
  size_t off = 0;
  auto alloc = [&](size_t bytes) -> void* {
    void* p = ws + off;
    off += (bytes + 255) & ~(size_t)255;
    return p;
  };
  _Float16* h1 = (_Float16*)alloc((size_t)N * 128 * 2);
  float* act1  = (float*)alloc((size_t)N * 128 * 4);
  _Float16* h2 = (_Float16*)alloc((size_t)N * 32 * 2);
  float* act2  = (float*)alloc((size_t)N * 32 * 4);
  float* as1   = (float*)alloc((size_t)N * 4 * 4);
  float* ad1   = (float*)alloc((size_t)N * 4 * 4);
  float* as2   = (float*)alloc((size_t)N * 4);
  float* ad2   = (float*)alloc((size_t)N * 4);
  int*   deg      = (int*)alloc((size_t)N * 4);
  int*   cursor   = (int*)alloc((size_t)N * 4);
  int*   rowStart = (int*)alloc((size_t)(N + 1) * 4);
  int*   colv     = (int*)alloc((size_t)E * 4);
  int*   partial  = (int*)alloc(4096);
  float* pooled   = (float*)alloc((size_t)G * 32 * 4);
  float* cntG     = (float*)alloc((size_t)G * 4);

  hipMemsetAsync(deg,    0, (size_t)N * 4, stream);
  hipMemsetAsync(cursor, 0, (size_t)N * 4, stream);
  hipMemsetAsync(pooled, 0, (size_t)G * 32 * 4, stream);
  hipMemsetAsync(cntG,   0, (size_t)G * 4, stream);

  // CSR by destination
  int eb = (E + 255) / 256;
  int nb = (N + SCAN_B - 1) / SCAN_B;
  degree_kernel<<<eb, 256, 0, stream>>>(dstv, deg, E);
  scan_partial_kernel<<<nb, SCAN_B, 0, stream>>>(deg, partial, N);
  scan_offsets_kernel<<<1, 256, 0, stream>>>(partial, nb);
  scan_final_kernel<<<nb, SCAN_B, 0, stream>>>(deg, partial, rowStart, N, E);
  fill_kernel<<<eb, 256, 0, stream>>>(srcv, dstv, rowStart, cursor, colv, E);

  // layer 1
  gemm1_kernel<<<(N + 7) / 8, 128, 0, stream>>>(x, W1, a_src1, a_dst1, h1, as1, ad1, N);
  gat_aggr3_kernel<128, 4><<<(N + 7) / 8, 256, 0, stream>>>(h1, as1, ad1, rowStart, colv, b1, act1, N);

  // layer 2
  gemm2_kernel<<<(N + 7) / 8, 128, 0, stream>>>(act1, W2, a_src2, a_dst2, h2, as2, ad2, N);
  gat_aggr3_kernel<32, 1><<<(N + 31) / 32, 256, 0, stream>>>(h2, as2, ad2, rowStart, colv, b2, act2, N);

  // pool + classify
  pool_kernel<<<(N + 63) / 64, 256, 0, stream>>>(act2, batch, pooled, cntG, N);
  classifier_kernel<<<(G + 255) / 256, 256, 0, stream>>>(pooled, cntG, Wc1, bc1, Wc2, bc2,
                                                         (float*)d_out, G);
}

// Round 2
// 417.514 us; speedup vs baseline: 1.2835x; 1.1949x over previous
//
#include <hip/hip_runtime.h>
#include <math.h>

#define SCAN_B 512
#define BUCKET_SHIFT 7                 // 128 nodes per bucket
#define BUCKET_NODES (1 << BUCKET_SHIFT)
#define MAX_BUCK 512                   // >= ceil(N / BUCKET_NODES)
#define PART_CHUNK 8192
#define PART_EPT 32                    // PART_CHUNK / 256

typedef _Float16 half4v __attribute__((ext_vector_type(4)));

__device__ __forceinline__ float leaky02(float x){ return x > 0.f ? x : 0.2f * x; }
__device__ __forceinline__ float eluf(float x){ return x > 0.f ? x : expm1f(x); }

// ---------------- GEMM1: h1 = x @ W1  (N x 128) @ (128 x 128), fused alpha dots ----
__global__ __launch_bounds__(128) void gemm1_kernel(
    const float* __restrict__ x, const float* __restrict__ W,
    const float* __restrict__ a_src, const float* __restrict__ a_dst, // flat [128]
    _Float16* __restrict__ h, float* __restrict__ as_, float* __restrict__ ad_, int n)
{
  const int t = threadIdx.x;
  const int row0 = blockIdx.x * 8;
  __shared__ float xs[8][128];
  __shared__ float sS[8][128];
  __shared__ float sD[8][128];
  for (int idx = t; idx < 8 * 32; idx += 128) {
    int r = idx >> 5, k4 = idx & 31;
    float4 v = (row0 + r < n) ? ((const float4*)x)[(size_t)(row0 + r) * 32 + k4]
                              : make_float4(0.f, 0.f, 0.f, 0.f);
    *(float4*)&xs[r][k4 * 4] = v;
  }
  __syncthreads();
  float acc[8] = {0,0,0,0,0,0,0,0};
  for (int k = 0; k < 128; k += 4) {
    float w0 = W[(k + 0) * 128 + t];
    float w1 = W[(k + 1) * 128 + t];
    float w2 = W[(k + 2) * 128 + t];
    float w3 = W[(k + 3) * 128 + t];
    #pragma unroll
    for (int r = 0; r < 8; ++r) {
      float4 xv = *(const float4*)&xs[r][k];
      acc[r] += xv.x * w0 + xv.y * w1 + xv.z * w2 + xv.w * w3;
    }
  }
  float asv = a_src[t], adv = a_dst[t];
  #pragma unroll
  for (int r = 0; r < 8; ++r) {
    float hv = acc[r];
    if (row0 + r < n) h[(size_t)(row0 + r) * 128 + t] = (_Float16)hv;
    sS[r][t] = hv * asv;
    sD[r][t] = hv * adv;
  }
  __syncthreads();
  if (t < 64) {
    int r = t >> 3, head = t & 3, which = (t >> 2) & 1;
    if (row0 + r < n) {
      const float (*buf)[128] = which ? sD : sS;
      double s = 0;
      for (int cc = 0; cc < 32; ++cc) s += (double)buf[r][head * 32 + cc];
      float* dstp = which ? ad_ : as_;
      dstp[(row0 + r) * 4 + head] = (float)s;
    }
  }
}

// ---------------- GEMM2: h2 = act1 @ W2 (N x 128) @ (128 x 32), fused alpha dots ---
__global__ __launch_bounds__(128) void gemm2_kernel(
    const float* __restrict__ x, const float* __restrict__ W,
    const float* __restrict__ a_src, const float* __restrict__ a_dst, // [32]
    _Float16* __restrict__ h, float* __restrict__ as_, float* __restrict__ ad_, int n)
{
  const int t = threadIdx.x;
  const int row0 = blockIdx.x * 8;
  __shared__ float xs[8][128];
  __shared__ float sH[8][32];
  for (int idx = t; idx < 8 * 32; idx += 128) {
    int r = idx >> 5, k4 = idx & 31;
    float4 v = (row0 + r < n) ? ((const float4*)x)[(size_t)(row0 + r) * 32 + k4]
                              : make_float4(0.f, 0.f, 0.f, 0.f);
    *(float4*)&xs[r][k4 * 4] = v;
  }
  __syncthreads();
  int col = t & 31, rp = t >> 5;
  int r0 = rp * 2, r1 = r0 + 1;
  float a0 = 0, a1 = 0;
  for (int k = 0; k < 128; k += 4) {
    float w0 = W[(k + 0) * 32 + col];
    float w1 = W[(k + 1) * 32 + col];
    float w2 = W[(k + 2) * 32 + col];
    float w3 = W[(k + 3) * 32 + col];
    float4 x0 = *(const float4*)&xs[r0][k];
    float4 x1 = *(const float4*)&xs[r1][k];
    a0 += x0.x * w0 + x0.y * w1 + x0.z * w2 + x0.w * w3;
    a1 += x1.x * w0 + x1.y * w1 + x1.z * w2 + x1.w * w3;
  }
  if (row0 + r0 < n) h[(size_t)(row0 + r0) * 32 + col] = (_Float16)a0;
  if (row0 + r1 < n) h[(size_t)(row0 + r1) * 32 + col] = (_Float16)a1;
  sH[r0][col] = a0; sH[r1][col] = a1;
  __syncthreads();
  if (t < 16) {
    int r = t >> 1, which = t & 1;
    if (row0 + r < n) {
      const float* a = which ? a_dst : a_src;
      double s = 0;
      for (int cc = 0; cc < 32; ++cc) s += (double)sH[r][cc] * (double)a[cc];
      (which ? ad_ : as_)[row0 + r] = (float)s;
    }
  }
}

// ---------------- CSR build v2: two-level counting sort ------------------------------
// Phase 1: per-block LDS histogram of dst-buckets (128 nodes/bucket)
__global__ __launch_bounds__(256) void bucket_hist_kernel(
    const int* __restrict__ dst, int* __restrict__ bucketCount, int E, int K)
{
  __shared__ int hist[MAX_BUCK];
  for (int b = threadIdx.x; b < K; b += 256) hist[b] = 0;
  __syncthreads();
  int cbase = blockIdx.x * PART_CHUNK;
  for (int j = 0; j < PART_EPT; ++j) {
    int e = cbase + j * 256 + threadIdx.x;
    if (e < E) atomicAdd(&hist[dst[e] >> BUCKET_SHIFT], 1);
  }
  __syncthreads();
  for (int b = threadIdx.x; b < K; b += 256)
    if (hist[b]) atomicAdd(&bucketCount[b], hist[b]);
}

// Phase 3: ranged-reservation partition. Each block reserves one contiguous run
// per bucket (single global atomic), then writes its records contiguously.
__global__ __launch_bounds__(256) void partition_kernel(
    const int* __restrict__ src, const int* __restrict__ dst,
    const int* __restrict__ bucketStart, int* __restrict__ cursorB,
    int2* __restrict__ bucketed, int E, int K)
{
  __shared__ int hist[MAX_BUCK];
  __shared__ int base_s[MAX_BUCK];
  __shared__ int cur[MAX_BUCK];
  for (int b = threadIdx.x; b < K; b += 256) hist[b] = 0;
  __syncthreads();
  int cbase = blockIdx.x * PART_CHUNK;
  for (int j = 0; j < PART_EPT; ++j) {
    int e = cbase + j * 256 + threadIdx.x;
    if (e < E) atomicAdd(&hist[dst[e] >> BUCKET_SHIFT], 1);
  }
  __syncthreads();
  for (int b = threadIdx.x; b < K; b += 256) {
    int c = hist[b];
    base_s[b] = c ? bucketStart[b] + atomicAdd(&cursorB[b], c) : 0;
    cur[b] = 0;
  }
  __syncthreads();
  for (int j = 0; j < PART_EPT; ++j) {
    int e = cbase + j * 256 + threadIdx.x;
    if (e < E) {
      int d = dst[e];
      int b = d >> BUCKET_SHIFT;
      int r = atomicAdd(&cur[b], 1);
      bucketed[base_s[b] + r] = make_int2(src[e], d);
    }
  }
}

// Phase 4: per-bucket node degrees via LDS histogram; coalesced deg writes
__global__ __launch_bounds__(256) void bucket_degree_kernel(
    const int2* __restrict__ bucketed, const int* __restrict__ bucketStart,
    int* __restrict__ deg, int n, int E, int K)
{
  int b = blockIdx.x;
  int nodeBase = b << BUCKET_SHIFT;
  __shared__ int hist[BUCKET_NODES];
  if (threadIdx.x < BUCKET_NODES) hist[threadIdx.x] = 0;
  __syncthreads();
  int bs = bucketStart[b];
  int be = (b + 1 < K) ? bucketStart[b + 1] : E;
  for (int i = bs + threadIdx.x; i < be; i += 256)
    atomicAdd(&hist[bucketed[i].y - nodeBase], 1);
  __syncthreads();
  int node = nodeBase + threadIdx.x;
  if (threadIdx.x < BUCKET_NODES && node < n) deg[node] = hist[threadIdx.x];
}

// Phase 6: per-bucket fine fill. Scatter confined to a ~16 KB col window (L2-resident),
// rank atomics in LDS.
__global__ __launch_bounds__(256) void fine_fill_kernel(
    const int2* __restrict__ bucketed, const int* __restrict__ bucketStart,
    const int* __restrict__ rowStart, int* __restrict__ col, int n, int E, int K)
{
  int b = blockIdx.x;
  int nodeBase = b << BUCKET_SHIFT;
  __shared__ int rs[BUCKET_NODES];
  __shared__ int cur[BUCKET_NODES];
  if (threadIdx.x < BUCKET_NODES) {
    int node = nodeBase + threadIdx.x;
    rs[threadIdx.x] = (node < n) ? rowStart[node] : 0;
    cur[threadIdx.x] = 0;
  }
  __syncthreads();
  int bs = bucketStart[b];
  int be = (b + 1 < K) ? bucketStart[b + 1] : E;
  for (int i = bs + threadIdx.x; i < be; i += 256) {
    int2 rec = bucketed[i];
    int local = rec.y - nodeBase;
    int pos = rs[local] + atomicAdd(&cur[local], 1);
    col[pos] = rec.x;
  }
}

__global__ __launch_bounds__(SCAN_B) void scan_partial_kernel(
    const int* __restrict__ deg, int* __restrict__ partial, int n)
{
  __shared__ int s[SCAN_B];
  int i = blockIdx.x * SCAN_B + threadIdx.x;
  s[threadIdx.x] = (i < n) ? deg[i] : 0;
  __syncthreads();
  for (int off = SCAN_B / 2; off > 0; off >>= 1) {
    if (threadIdx.x < off) s[threadIdx.x] += s[threadIdx.x + off];
    __syncthreads();
  }
  if (threadIdx.x == 0) partial[blockIdx.x] = s[0];
}

// single-block parallel exclusive scan (in-place) over nb ints
__global__ __launch_bounds__(256) void scan_offsets_kernel(int* __restrict__ partial, int nb) {
  __shared__ int s[256];
  __shared__ int carry_s;
  int t = threadIdx.x;
  if (t == 0) carry_s = 0;
  __syncthreads();
  for (int b = 0; b < nb; b += 256) {
    int v = (b + t < nb) ? partial[b + t] : 0;
    s[t] = v;
    __syncthreads();
    for (int off = 1; off < 256; off <<= 1) {
      int x = (t >= off) ? s[t - off] : 0;
      __syncthreads();
      s[t] += x;
      __syncthreads();
    }
    int incl = s[t];
    int carry = carry_s;
    if (b + t < nb) partial[b + t] = carry + incl - v;   // exclusive
    __syncthreads();
    if (t == 255) carry_s = carry + incl;
    __syncthreads();
  }
}

__global__ __launch_bounds__(SCAN_B) void scan_final_kernel(
    const int* __restrict__ deg, const int* __restrict__ partial,
    int* __restrict__ rowStart, int n, int Etot)
{
  __shared__ int s[SCAN_B];
  int i = blockIdx.x * SCAN_B + threadIdx.x;
  int v = (i < n) ? deg[i] : 0;
  s[threadIdx.x] = v;
  __syncthreads();
  for (int off = 1; off < SCAN_B; off <<= 1) {
    int xv = (threadIdx.x >= off) ? s[threadIdx.x - off] : 0;
    __syncthreads();
    s[threadIdx.x] += xv;
    __syncthreads();
  }
  if (i < n) rowStart[i] = partial[blockIdx.x] + s[threadIdx.x] - v;  // exclusive scan
  if (i == 0) rowStart[n] = Etot;
}

// ---------------- GAT aggregation: wave-private, barrier-free, fp16 features --------
template<int CTOT, int H>
__global__ __launch_bounds__(256) void gat_aggr3_kernel(
    const _Float16* __restrict__ feat,  // [n, CTOT] fp16
    const float* __restrict__ as_,      // [n, H]
    const float* __restrict__ ad_,      // [n, H]
    const int* __restrict__ rowStart,
    const int* __restrict__ col,
    const float* __restrict__ bias,     // [CTOT]
    float* __restrict__ out, int n)
{
  constexpr int L    = CTOT / 4;   // lanes per node
  constexpr int NPW  = 64 / L;     // nodes per wave
  constexpr int NPB  = 4 * NPW;    // nodes per block (256 thr = 4 waves)
  constexpr int CH   = CTOT / H;   // channels per head
  constexpr int CHUNK = L;         // edges staged per round

  const int t    = threadIdx.x;
  const int wave = t >> 6;
  const int lane = t & 63;
  const int grp  = lane / L;
  const int li   = lane % L;
  const int slot = wave * NPW + grp;
  const int node = blockIdx.x * NPB + slot;
  const int hc   = (4 * li) / CH;

  __shared__ int   s_off[NPB][CHUNK + 1];
  __shared__ float s_p[NPB][CHUNK * H + 1];

  if (node >= n) return;   // safe: no barriers below

  const int beg = rowStart[node];
  const int deg = rowStart[node + 1] - beg;

  float adv[H], eself[H];
  #pragma unroll
  for (int h = 0; h < H; ++h) adv[h] = ad_[node * H + h];
  #pragma unroll
  for (int h = 0; h < H; ++h) eself[h] = leaky02(as_[node * H + h] + adv[h]);

  float es = 0.f;
  #pragma unroll
  for (int h = 0; h < H; ++h) if (h == hc) es = eself[h];
  const float ps = expf(es);

  const half4v fself = *(const half4v*)(feat + (size_t)node * CTOT + 4 * li);
  double acc64[4];
  acc64[0] = (double)ps * (double)(float)fself.x;
  acc64[1] = (double)ps * (double)(float)fself.y;
  acc64[2] = (double)ps * (double)(float)fself.z;
  acc64[3] = (double)ps * (double)(float)fself.w;
  double den64 = (double)ps;

  for (int base = 0; base < deg; base += CHUNK) {
    const int cnt = min(CHUNK, deg - base);
    if (li < cnt) {
      int s = col[beg + base + li];
      s_off[slot][li] = s * CTOT;
      if constexpr (H == 4) {
        float4 q = ((const float4*)as_)[s];
        s_p[slot][li * 4 + 0] = expf(leaky02(q.x + adv[0]));
        s_p[slot][li * 4 + 1] = expf(leaky02(q.y + adv[1]));
        s_p[slot][li * 4 + 2] = expf(leaky02(q.z + adv[2]));
        s_p[slot][li * 4 + 3] = expf(leaky02(q.w + adv[3]));
      } else {
        s_p[slot][li] = expf(leaky02(as_[s] + adv[0]));
      }
    }
    __builtin_amdgcn_wave_barrier();   // keep staging before consumption
    float a0 = 0.f, a1 = 0.f, a2 = 0.f, a3 = 0.f, df = 0.f;
    #pragma unroll 8
    for (int j = 0; j < cnt; ++j) {
      int off = s_off[slot][j];
      float p = (H == 4) ? s_p[slot][j * 4 + hc] : s_p[slot][j];
      const half4v f = *(const half4v*)(feat + off + 4 * li);
      a0 += p * (float)f.x; a1 += p * (float)f.y;
      a2 += p * (float)f.z; a3 += p * (float)f.w;
      df += p;
    }
    __builtin_amdgcn_wave_barrier();   // keep consumption before next staging
    acc64[0] += a0; acc64[1] += a1; acc64[2] += a2; acc64[3] += a3;
    den64 += df;
  }

  const float4 bv = *(const float4*)(bias + 4 * li);
  float4 o;
  o.x = eluf((float)(acc64[0] / den64) + bv.x);
  o.y = eluf((float)(acc64[1] / den64) + bv.y);
  o.z = eluf((float)(acc64[2] / den64) + bv.z);
  o.w = eluf((float)(acc64[3] / den64) + bv.w);
  *(float4*)(out + (size_t)node * CTOT + 4 * li) = o;
}

// ---------------- pooling (batch is sorted: run-length flush) -----------------------
__global__ __launch_bounds__(256) void pool_kernel(const float* __restrict__ act2,
    const int* __restrict__ batch, float* __restrict__ pooled,
    float* __restrict__ cnt, int n)
{
  int t = threadIdx.x;
  int c = t & 31, r = t >> 5;
  int n0 = blockIdx.x * 64 + r * 8;
  float run = 0.f; int gcur = -1; int len = 0;
  for (int i = 0; i < 8; ++i) {
    int nd = n0 + i;
    if (nd >= n) break;
    int gb = batch[nd];
    if (gb != gcur) {
      if (gcur >= 0) {
        atomicAdd(&pooled[gcur * 32 + c], run);
        if (c == 0) atomicAdd(&cnt[gcur], (float)len);
      }
      gcur = gb; run = 0.f; len = 0;
    }
    run += act2[(size_t)nd * 32 + c];
    len++;
  }
  if (gcur >= 0) {
    atomicAdd(&pooled[gcur * 32 + c], run);
    if (c == 0) atomicAdd(&cnt[gcur], (float)len);
  }
}

__global__ void classifier_kernel(const float* __restrict__ pooled, const float* __restrict__ cnt,
    const float* __restrict__ Wc1, const float* __restrict__ bc1,
    const float* __restrict__ Wc2, const float* __restrict__ bc2,
    float* __restrict__ outp, int g_total)
{
  int g = blockIdx.x * blockDim.x + threadIdx.x;
  if (g < g_total) {
    float inv = 1.0f / cnt[g];
    float pm[32];
    for (int c = 0; c < 32; ++c) pm[c] = pooled[g * 32 + c] * inv;
    double o = (double)bc2[0];
    for (int j = 0; j < 16; ++j) {
      double z = (double)bc1[j];
      for (int c = 0; c < 32; ++c) z += (double)pm[c] * (double)Wc1[c * 16 + j];
      float zr = (float)z;
      zr = zr > 0.f ? zr : 0.f;
      o += (double)zr * (double)Wc2[j];
    }
    outp[g] = (float)o;
  }
}

// ---------------- launch ------------------------------------------------------------
extern "C" void kernel_launch(void* const* d_in, const int* in_sizes, int n_in,
                              void* d_out, int out_size, void* d_ws, size_t ws_size,
                              hipStream_t stream)
{
  const float* x      = (const float*)d_in[0];
  const int*   ei     = (const int*)d_in[1];
  const int*   batch  = (const int*)d_in[3];
  const float* W1     = (const float*)d_in[4];
  const float* a_src1 = (const float*)d_in[5];
  const float* a_dst1 = (const float*)d_in[6];
  const float* b1     = (const float*)d_in[7];
  const float* W2     = (const float*)d_in[8];
  const float* a_src2 = (const float*)d_in[9];
  const float* a_dst2 = (const float*)d_in[10];
  const float* b2     = (const float*)d_in[11];
  const float* Wc1    = (const float*)d_in[12];
  const float* bc1    = (const float*)d_in[13];
  const float* Wc2    = (const float*)d_in[14];
  const float* bc2    = (const float*)d_in[15];

  const int N = in_sizes[0] / 128;
  const int E = in_sizes[1] / 2;
  const int G = out_size;

  const int* srcv = ei;
  const int* dstv = ei + E;

  char* ws = (char*)d_ws;
  size_t off = 0;
  auto alloc = [&](size_t bytes) -> void* {
    void* p = ws + off;
    off += (bytes + 255) & ~(size_t)255;
    return p;
  };
  _Float16* h1 = (_Float16*)alloc((size_t)N * 128 * 2);
  float* act1  = (float*)alloc((size_t)N * 128 * 4);
  _Float16* h2 = (_Float16*)alloc((size_t)N * 32 * 2);
  float* act2  = (float*)alloc((size_t)N * 32 * 4);
  float* as1   = (float*)alloc((size_t)N * 4 * 4);
  float* ad1   = (float*)alloc((size_t)N * 4 * 4);
  float* as2   = (float*)alloc((size_t)N * 4);
  float* ad2   = (float*)alloc((size_t)N * 4);
  int*   deg      = (int*)alloc((size_t)N * 4);
  int*   rowStart = (int*)alloc((size_t)(N + 1) * 4);
  int*   colv     = (int*)alloc((size_t)E * 4);
  int*   partial  = (int*)alloc(4096);
  int*   bucketCount = (int*)alloc((size_t)MAX_BUCK * 4);  // becomes bucketStart after scan
  int*   cursorB     = (int*)alloc((size_t)MAX_BUCK * 4);
  int2*  bucketed    = (int2*)alloc((size_t)E * 8);
  float* pooled   = (float*)alloc((size_t)G * 32 * 4);
  float* cntG     = (float*)alloc((size_t)G * 4);

  const int K = (N + BUCKET_NODES - 1) >> BUCKET_SHIFT;   // buckets (<= MAX_BUCK)

  hipMemsetAsync(bucketCount, 0, (size_t)K * 4, stream);
  hipMemsetAsync(cursorB,     0, (size_t)K * 4, stream);
  hipMemsetAsync(pooled, 0, (size_t)G * 32 * 4, stream);
  hipMemsetAsync(cntG,   0, (size_t)G * 4, stream);

  // CSR by destination — two-level counting sort
  int pb = (E + PART_CHUNK - 1) / PART_CHUNK;
  int nb = (N + SCAN_B - 1) / SCAN_B;
  bucket_hist_kernel<<<pb, 256, 0, stream>>>(dstv, bucketCount, E, K);
  scan_offsets_kernel<<<1, 256, 0, stream>>>(bucketCount, K);        // -> bucketStart
  partition_kernel<<<pb, 256, 0, stream>>>(srcv, dstv, bucketCount, cursorB, bucketed, E, K);
  bucket_degree_kernel<<<K, 256, 0, stream>>>(bucketed, bucketCount, deg, N, E, K);
  scan_partial_kernel<<<nb, SCAN_B, 0, stream>>>(deg, partial, N);
  scan_offsets_kernel<<<1, 256, 0, stream>>>(partial, nb);
  scan_final_kernel<<<nb, SCAN_B, 0, stream>>>(deg, partial, rowStart, N, E);
  fine_fill_kernel<<<K, 256, 0, stream>>>(bucketed, bucketCount, rowStart, colv, N, E, K);

  // layer 1
  gemm1_kernel<<<(N + 7) / 8, 128, 0, stream>>>(x, W1, a_src1, a_dst1, h1, as1, ad1, N);
  gat_aggr3_kernel<128, 4><<<(N + 7) / 8, 256, 0, stream>>>(h1, as1, ad1, rowStart, colv, b1, act1, N);

  // layer 2
  gemm2_kernel<<<(N + 7) / 8, 128, 0, stream>>>(act1, W2, a_src2, a_dst2, h2, as2, ad2, N);
  gat_aggr3_kernel<32, 1><<<(N + 31) / 32, 256, 0, stream>>>(h2, as2, ad2, rowStart, colv, b2, act2, N);

  // pool + classify
  pool_kernel<<<(N + 63) / 64, 256, 0, stream>>>(act2, batch, pooled, cntG, N);
  classifier_kernel<<<(G + 255) / 256, 256, 0, stream>>>(pooled, cntG, Wc1, bc1, Wc2, bc2,
                                                         (float*)d_out, G);
}

// Round 3
// 398.317 us; speedup vs baseline: 1.3454x; 1.0482x over previous
//
#include <hip/hip_runtime.h>
#include <math.h>

#define BUCKET_SHIFT 7                 // 128 nodes per bucket
#define BUCKET_NODES (1 << BUCKET_SHIFT)
#define MAX_BUCK 512                   // >= ceil(N / BUCKET_NODES)
#define PART_CHUNK 8192
#define PART_EPT 32                    // PART_CHUNK / 256

typedef _Float16 half4v __attribute__((ext_vector_type(4)));
typedef _Float16 half8v __attribute__((ext_vector_type(8)));

__device__ __forceinline__ float leaky02(float x){ return x > 0.f ? x : 0.2f * x; }
__device__ __forceinline__ float eluf(float x){ return x > 0.f ? x : expm1f(x); }

// ---------------- GEMM1: h1 = x @ W1  (N x 128) @ (128 x 128), fused alpha dots ----
__global__ __launch_bounds__(128) void gemm1_kernel(
    const float* __restrict__ x, const float* __restrict__ W,
    const float* __restrict__ a_src, const float* __restrict__ a_dst, // flat [128]
    _Float16* __restrict__ h, float* __restrict__ as_, float* __restrict__ ad_, int n)
{
  const int t = threadIdx.x;
  const int row0 = blockIdx.x * 8;
  __shared__ float xs[8][128];
  __shared__ float sS[8][128];
  __shared__ float sD[8][128];
  for (int idx = t; idx < 8 * 32; idx += 128) {
    int r = idx >> 5, k4 = idx & 31;
    float4 v = (row0 + r < n) ? ((const float4*)x)[(size_t)(row0 + r) * 32 + k4]
                              : make_float4(0.f, 0.f, 0.f, 0.f);
    *(float4*)&xs[r][k4 * 4] = v;
  }
  __syncthreads();
  float acc[8] = {0,0,0,0,0,0,0,0};
  for (int k = 0; k < 128; k += 4) {
    float w0 = W[(k + 0) * 128 + t];
    float w1 = W[(k + 1) * 128 + t];
    float w2 = W[(k + 2) * 128 + t];
    float w3 = W[(k + 3) * 128 + t];
    #pragma unroll
    for (int r = 0; r < 8; ++r) {
      float4 xv = *(const float4*)&xs[r][k];
      acc[r] += xv.x * w0 + xv.y * w1 + xv.z * w2 + xv.w * w3;
    }
  }
  float asv = a_src[t], adv = a_dst[t];
  #pragma unroll
  for (int r = 0; r < 8; ++r) {
    float hv = acc[r];
    if (row0 + r < n) h[(size_t)(row0 + r) * 128 + t] = (_Float16)hv;
    sS[r][t] = hv * asv;
    sD[r][t] = hv * adv;
  }
  __syncthreads();
  if (t < 64) {
    int r = t >> 3, head = t & 3, which = (t >> 2) & 1;
    if (row0 + r < n) {
      const float (*buf)[128] = which ? sD : sS;
      double s = 0;
      for (int cc = 0; cc < 32; ++cc) s += (double)buf[r][head * 32 + cc];
      float* dstp = which ? ad_ : as_;
      dstp[(row0 + r) * 4 + head] = (float)s;
    }
  }
}

// ---------------- GEMM2: h2 = act1 @ W2 (N x 128 fp16) @ (128 x 32), fused alphas ---
__global__ __launch_bounds__(128) void gemm2_kernel(
    const _Float16* __restrict__ x, const float* __restrict__ W,
    const float* __restrict__ a_src, const float* __restrict__ a_dst, // [32]
    _Float16* __restrict__ h, float* __restrict__ as_, float* __restrict__ ad_, int n)
{
  const int t = threadIdx.x;
  const int row0 = blockIdx.x * 8;
  __shared__ float xs[8][128];
  __shared__ float sH[8][32];
  for (int idx = t; idx < 8 * 16; idx += 128) {
    int r = idx >> 4, k8 = idx & 15;
    half8v v;
    #pragma unroll
    for (int q = 0; q < 8; ++q) v[q] = (_Float16)0.f;
    if (row0 + r < n) v = ((const half8v*)x)[(size_t)(row0 + r) * 16 + k8];
    #pragma unroll
    for (int q = 0; q < 8; ++q) xs[r][k8 * 8 + q] = (float)v[q];
  }
  __syncthreads();
  int col = t & 31, rp = t >> 5;
  int r0 = rp * 2, r1 = r0 + 1;
  float a0 = 0, a1 = 0;
  for (int k = 0; k < 128; k += 4) {
    float w0 = W[(k + 0) * 32 + col];
    float w1 = W[(k + 1) * 32 + col];
    float w2 = W[(k + 2) * 32 + col];
    float w3 = W[(k + 3) * 32 + col];
    float4 x0 = *(const float4*)&xs[r0][k];
    float4 x1 = *(const float4*)&xs[r1][k];
    a0 += x0.x * w0 + x0.y * w1 + x0.z * w2 + x0.w * w3;
    a1 += x1.x * w0 + x1.y * w1 + x1.z * w2 + x1.w * w3;
  }
  if (row0 + r0 < n) h[(size_t)(row0 + r0) * 32 + col] = (_Float16)a0;
  if (row0 + r1 < n) h[(size_t)(row0 + r1) * 32 + col] = (_Float16)a1;
  sH[r0][col] = a0; sH[r1][col] = a1;
  __syncthreads();
  if (t < 16) {
    int r = t >> 1, which = t & 1;
    if (row0 + r < n) {
      const float* a = which ? a_dst : a_src;
      double s = 0;
      for (int cc = 0; cc < 32; ++cc) s += (double)sH[r][cc] * (double)a[cc];
      (which ? ad_ : as_)[row0 + r] = (float)s;
    }
  }
}

// ---------------- CSR build: two-level counting sort --------------------------------
__global__ __launch_bounds__(256) void bucket_hist_kernel(
    const int* __restrict__ dst, int* __restrict__ bucketCount, int E, int K)
{
  __shared__ int hist[MAX_BUCK];
  for (int b = threadIdx.x; b < K; b += 256) hist[b] = 0;
  __syncthreads();
  int cbase = blockIdx.x * PART_CHUNK;
  for (int j = 0; j < PART_EPT; ++j) {
    int e = cbase + j * 256 + threadIdx.x;
    if (e < E) atomicAdd(&hist[dst[e] >> BUCKET_SHIFT], 1);
  }
  __syncthreads();
  for (int b = threadIdx.x; b < K; b += 256)
    if (hist[b]) atomicAdd(&bucketCount[b], hist[b]);
}

// Ranged-reservation partition: one global atomic per (block,bucket) run.
__global__ __launch_bounds__(256) void partition_kernel(
    const int* __restrict__ src, const int* __restrict__ dst,
    const int* __restrict__ bucketStart, int* __restrict__ cursorB,
    int2* __restrict__ bucketed, int E, int K)
{
  __shared__ int hist[MAX_BUCK];
  __shared__ int base_s[MAX_BUCK];
  __shared__ int cur[MAX_BUCK];
  for (int b = threadIdx.x; b < K; b += 256) hist[b] = 0;
  __syncthreads();
  int cbase = blockIdx.x * PART_CHUNK;
  for (int j = 0; j < PART_EPT; ++j) {
    int e = cbase + j * 256 + threadIdx.x;
    if (e < E) atomicAdd(&hist[dst[e] >> BUCKET_SHIFT], 1);
  }
  __syncthreads();
  for (int b = threadIdx.x; b < K; b += 256) {
    int c = hist[b];
    base_s[b] = c ? bucketStart[b] + atomicAdd(&cursorB[b], c) : 0;
    cur[b] = 0;
  }
  __syncthreads();
  for (int j = 0; j < PART_EPT; ++j) {
    int e = cbase + j * 256 + threadIdx.x;
    if (e < E) {
      int d = dst[e];
      int b = d >> BUCKET_SHIFT;
      int r = atomicAdd(&cur[b], 1);
      bucketed[base_s[b] + r] = make_int2(src[e], d);
    }
  }
}

// Fused per-bucket: LDS histogram -> 128-wide scan -> rowStart write -> fine fill.
// Global CSR order == bucket-major/node-minor, so local scan + bucketStart IS rowStart.
__global__ __launch_bounds__(256) void fill_csr_kernel(
    const int2* __restrict__ bucketed, const int* __restrict__ bucketStart,
    int* __restrict__ rowStart, int* __restrict__ col, int n, int E, int K)
{
  int b = blockIdx.x;
  int nodeBase = b << BUCKET_SHIFT;
  int t = threadIdx.x;
  __shared__ int hist[BUCKET_NODES];
  __shared__ int rs[BUCKET_NODES];
  __shared__ int cur[BUCKET_NODES];
  if (t < BUCKET_NODES) hist[t] = 0;
  __syncthreads();
  int bs = bucketStart[b];
  int be = (b + 1 < K) ? bucketStart[b + 1] : E;
  for (int i = bs + t; i < be; i += 256)
    atomicAdd(&hist[bucketed[i].y - nodeBase], 1);
  __syncthreads();
  if (t < BUCKET_NODES) rs[t] = hist[t];
  __syncthreads();
  for (int off = 1; off < BUCKET_NODES; off <<= 1) {
    int v = (t < BUCKET_NODES && t >= off) ? rs[t - off] : 0;
    __syncthreads();
    if (t < BUCKET_NODES) rs[t] += v;
    __syncthreads();
  }
  if (t < BUCKET_NODES) {
    int node = nodeBase + t;
    int excl = bs + rs[t] - hist[t];      // exclusive start, absolute
    if (node < n) rowStart[node] = excl;
    rs[t] = excl;
    cur[t] = 0;
  }
  if (b == K - 1 && t == 0) rowStart[n] = E;
  __syncthreads();
  for (int i = bs + t; i < be; i += 256) {
    int2 rec = bucketed[i];
    int local = rec.y - nodeBase;
    int pos = rs[local] + atomicAdd(&cur[local], 1);
    col[pos] = rec.x;
  }
}

// ---------------- GAT aggregation layer 1: 16 lanes/node, half8 loads, fp16 out -----
__global__ __launch_bounds__(256) void gat_aggr_w16_kernel(
    const _Float16* __restrict__ feat,  // [n, 128] fp16
    const float* __restrict__ as_,      // [n, 4]
    const float* __restrict__ ad_,      // [n, 4]
    const int* __restrict__ rowStart,
    const int* __restrict__ col,
    const float* __restrict__ bias,     // [128]
    _Float16* __restrict__ out, int n)  // [n, 128] fp16
{
  constexpr int L    = 16;   // lanes per node
  constexpr int NPW  = 4;    // nodes per wave
  constexpr int NPB  = 16;   // nodes per block
  constexpr int CHUNK = 16;  // edges staged per round

  const int t    = threadIdx.x;
  const int wave = t >> 6;
  const int lane = t & 63;
  const int grp  = lane >> 4;
  const int li   = lane & 15;
  const int slot = wave * NPW + grp;
  const int node = blockIdx.x * NPB + slot;
  const int hc   = li >> 2;          // head for this lane's 8 channels

  __shared__ int   s_off[NPB][CHUNK + 1];
  __shared__ float s_p[NPB][CHUNK * 4 + 1];

  if (node >= n) return;   // safe: no block barriers below

  const int beg = rowStart[node];
  const int deg = rowStart[node + 1] - beg;

  const float4 advv = ((const float4*)ad_)[node];
  const float4 asvv = ((const float4*)as_)[node];
  float adv[4] = {advv.x, advv.y, advv.z, advv.w};
  float eself[4];
  eself[0] = leaky02(asvv.x + adv[0]);
  eself[1] = leaky02(asvv.y + adv[1]);
  eself[2] = leaky02(asvv.z + adv[2]);
  eself[3] = leaky02(asvv.w + adv[3]);
  float es = 0.f;
  #pragma unroll
  for (int h = 0; h < 4; ++h) if (h == hc) es = eself[h];
  const float ps = expf(es);

  const char* featc = (const char*)feat + (li << 4);   // +16B per lane
  const half8v fself = *(const half8v*)(featc + ((size_t)node << 8));
  double acc64[8];
  #pragma unroll
  for (int q = 0; q < 8; ++q) acc64[q] = (double)ps * (double)(float)fself[q];
  double den64 = (double)ps;

  for (int base = 0; base < deg; base += CHUNK) {
    const int cnt = min(CHUNK, deg - base);
    if (li < cnt) {
      int s = col[beg + base + li];
      s_off[slot][li] = s << 8;                 // byte offset of source row
      float4 q = ((const float4*)as_)[s];
      s_p[slot][li * 4 + 0] = expf(leaky02(q.x + adv[0]));
      s_p[slot][li * 4 + 1] = expf(leaky02(q.y + adv[1]));
      s_p[slot][li * 4 + 2] = expf(leaky02(q.z + adv[2]));
      s_p[slot][li * 4 + 3] = expf(leaky02(q.w + adv[3]));
    }
    __builtin_amdgcn_wave_barrier();   // staging before consumption
    float a[8] = {0,0,0,0,0,0,0,0};
    float df = 0.f;
    #pragma unroll 4
    for (int j = 0; j < cnt; ++j) {
      int boff = s_off[slot][j];
      float p = s_p[slot][j * 4 + hc];
      const half8v f = *(const half8v*)(featc + boff);
      #pragma unroll
      for (int q = 0; q < 8; ++q) a[q] += p * (float)f[q];
      df += p;
    }
    __builtin_amdgcn_wave_barrier();   // consumption before next staging
    #pragma unroll
    for (int q = 0; q < 8; ++q) acc64[q] += a[q];
    den64 += df;
  }

  const float4 bv0 = ((const float4*)bias)[2 * li];
  const float4 bv1 = ((const float4*)bias)[2 * li + 1];
  const float bb[8] = {bv0.x, bv0.y, bv0.z, bv0.w, bv1.x, bv1.y, bv1.z, bv1.w};
  const double inv = 1.0 / den64;
  half8v ov;
  #pragma unroll
  for (int q = 0; q < 8; ++q)
    ov[q] = (_Float16)eluf((float)(acc64[q] * inv) + bb[q]);
  *(half8v*)((char*)out + ((size_t)node << 8) + (li << 4)) = ov;
}

// ---------------- GAT aggregation layer 2: wave-private, fp16 features, f32 out -----
template<int CTOT, int H>
__global__ __launch_bounds__(256) void gat_aggr3_kernel(
    const _Float16* __restrict__ feat,  // [n, CTOT] fp16
    const float* __restrict__ as_,      // [n, H]
    const float* __restrict__ ad_,      // [n, H]
    const int* __restrict__ rowStart,
    const int* __restrict__ col,
    const float* __restrict__ bias,     // [CTOT]
    float* __restrict__ out, int n)
{
  constexpr int L    = CTOT / 4;   // lanes per node
  constexpr int NPW  = 64 / L;     // nodes per wave
  constexpr int NPB  = 4 * NPW;    // nodes per block (256 thr = 4 waves)
  constexpr int CH   = CTOT / H;   // channels per head
  constexpr int CHUNK = L;         // edges staged per round

  const int t    = threadIdx.x;
  const int wave = t >> 6;
  const int lane = t & 63;
  const int grp  = lane / L;
  const int li   = lane % L;
  const int slot = wave * NPW + grp;
  const int node = blockIdx.x * NPB + slot;
  const int hc   = (4 * li) / CH;

  __shared__ int   s_off[NPB][CHUNK + 1];
  __shared__ float s_p[NPB][CHUNK * H + 1];

  if (node >= n) return;   // safe: no barriers below

  const int beg = rowStart[node];
  const int deg = rowStart[node + 1] - beg;

  float adv[H], eself[H];
  #pragma unroll
  for (int h = 0; h < H; ++h) adv[h] = ad_[node * H + h];
  #pragma unroll
  for (int h = 0; h < H; ++h) eself[h] = leaky02(as_[node * H + h] + adv[h]);

  float es = 0.f;
  #pragma unroll
  for (int h = 0; h < H; ++h) if (h == hc) es = eself[h];
  const float ps = expf(es);

  const half4v fself = *(const half4v*)(feat + (size_t)node * CTOT + 4 * li);
  double acc64[4];
  acc64[0] = (double)ps * (double)(float)fself.x;
  acc64[1] = (double)ps * (double)(float)fself.y;
  acc64[2] = (double)ps * (double)(float)fself.z;
  acc64[3] = (double)ps * (double)(float)fself.w;
  double den64 = (double)ps;

  for (int base = 0; base < deg; base += CHUNK) {
    const int cnt = min(CHUNK, deg - base);
    if (li < cnt) {
      int s = col[beg + base + li];
      s_off[slot][li] = s * CTOT;
      if constexpr (H == 4) {
        float4 q = ((const float4*)as_)[s];
        s_p[slot][li * 4 + 0] = expf(leaky02(q.x + adv[0]));
        s_p[slot][li * 4 + 1] = expf(leaky02(q.y + adv[1]));
        s_p[slot][li * 4 + 2] = expf(leaky02(q.z + adv[2]));
        s_p[slot][li * 4 + 3] = expf(leaky02(q.w + adv[3]));
      } else {
        s_p[slot][li] = expf(leaky02(as_[s] + adv[0]));
      }
    }
    __builtin_amdgcn_wave_barrier();   // staging before consumption
    float a0 = 0.f, a1 = 0.f, a2 = 0.f, a3 = 0.f, df = 0.f;
    #pragma unroll 8
    for (int j = 0; j < cnt; ++j) {
      int off = s_off[slot][j];
      float p = (H == 4) ? s_p[slot][j * 4 + hc] : s_p[slot][j];
      const half4v f = *(const half4v*)(feat + off + 4 * li);
      a0 += p * (float)f.x; a1 += p * (float)f.y;
      a2 += p * (float)f.z; a3 += p * (float)f.w;
      df += p;
    }
    __builtin_amdgcn_wave_barrier();   // consumption before next staging
    acc64[0] += a0; acc64[1] += a1; acc64[2] += a2; acc64[3] += a3;
    den64 += df;
  }

  const float4 bv = *(const float4*)(bias + 4 * li);
  float4 o;
  o.x = eluf((float)(acc64[0] / den64) + bv.x);
  o.y = eluf((float)(acc64[1] / den64) + bv.y);
  o.z = eluf((float)(acc64[2] / den64) + bv.z);
  o.w = eluf((float)(acc64[3] / den64) + bv.w);
  *(float4*)(out + (size_t)node * CTOT + 4 * li) = o;
}

// ---------------- pooling (batch is sorted: run-length flush) -----------------------
__global__ __launch_bounds__(256) void pool_kernel(const float* __restrict__ act2,
    const int* __restrict__ batch, float* __restrict__ pooled,
    float* __restrict__ cnt, int n)
{
  int t = threadIdx.x;
  int c = t & 31, r = t >> 5;
  int n0 = blockIdx.x * 64 + r * 8;
  float run = 0.f; int gcur = -1; int len = 0;
  for (int i = 0; i < 8; ++i) {
    int nd = n0 + i;
    if (nd >= n) break;
    int gb = batch[nd];
    if (gb != gcur) {
      if (gcur >= 0) {
        atomicAdd(&pooled[gcur * 32 + c], run);
        if (c == 0) atomicAdd(&cnt[gcur], (float)len);
      }
      gcur = gb; run = 0.f; len = 0;
    }
    run += act2[(size_t)nd * 32 + c];
    len++;
  }
  if (gcur >= 0) {
    atomicAdd(&pooled[gcur * 32 + c], run);
    if (c == 0) atomicAdd(&cnt[gcur], (float)len);
  }
}

__global__ void classifier_kernel(const float* __restrict__ pooled, const float* __restrict__ cnt,
    const float* __restrict__ Wc1, const float* __restrict__ bc1,
    const float* __restrict__ Wc2, const float* __restrict__ bc2,
    float* __restrict__ outp, int g_total)
{
  int g = blockIdx.x * blockDim.x + threadIdx.x;
  if (g < g_total) {
    float inv = 1.0f / cnt[g];
    float pm[32];
    for (int c = 0; c < 32; ++c) pm[c] = pooled[g * 32 + c] * inv;
    double o = (double)bc2[0];
    for (int j = 0; j < 16; ++j) {
      double z = (double)bc1[j];
      for (int c = 0; c < 32; ++c) z += (double)pm[c] * (double)Wc1[c * 16 + j];
      float zr = (float)z;
      zr = zr > 0.f ? zr : 0.f;
      o += (double)zr * (double)Wc2[j];
    }
    outp[g] = (float)o;
  }
}

// ---------------- launch ------------------------------------------------------------
extern "C" void kernel_launch(void* const* d_in, const int* in_sizes, int n_in,
                              void* d_out, int out_size, void* d_ws, size_t ws_size,
                              hipStream_t stream)
{
  const float* x      = (const float*)d_in[0];
  const int*   ei     = (const int*)d_in[1];
  const int*   batch  = (const int*)d_in[3];
  const float* W1     = (const float*)d_in[4];
  const float* a_src1 = (const float*)d_in[5];
  const float* a_dst1 = (const float*)d_in[6];
  const float* b1     = (const float*)d_in[7];
  const float* W2     = (const float*)d_in[8];
  const float* a_src2 = (const float*)d_in[9];
  const float* a_dst2 = (const float*)d_in[10];
  const float* b2     = (const float*)d_in[11];
  const float* Wc1    = (const float*)d_in[12];
  const float* bc1    = (const float*)d_in[13];
  const float* Wc2    = (const float*)d_in[14];
  const float* bc2    = (const float*)d_in[15];

  const int N = in_sizes[0] / 128;
  const int E = in_sizes[1] / 2;
  const int G = out_size;

  const int* srcv = ei;
  const int* dstv = ei + E;

  char* ws = (char*)d_ws;
  size_t off = 0;
  auto alloc = [&](size_t bytes) -> void* {
    void* p = ws + off;
    off += (bytes + 255) & ~(size_t)255;
    return p;
  };
  _Float16* h1   = (_Float16*)alloc((size_t)N * 128 * 2);
  _Float16* act1 = (_Float16*)alloc((size_t)N * 128 * 2);
  _Float16* h2   = (_Float16*)alloc((size_t)N * 32 * 2);
  float* act2  = (float*)alloc((size_t)N * 32 * 4);
  float* as1   = (float*)alloc((size_t)N * 4 * 4);
  float* ad1   = (float*)alloc((size_t)N * 4 * 4);
  float* as2   = (float*)alloc((size_t)N * 4);
  float* ad2   = (float*)alloc((size_t)N * 4);
  int*   rowStart = (int*)alloc((size_t)(N + 1) * 4);
  int*   colv     = (int*)alloc((size_t)E * 4);
  int*   bucketCount = (int*)alloc((size_t)MAX_BUCK * 4);  // -> bucketStart after scan
  int*   cursorB     = (int*)alloc((size_t)MAX_BUCK * 4);
  int2*  bucketed    = (int2*)alloc((size_t)E * 8);
  float* pooled   = (float*)alloc((size_t)G * 32 * 4);
  float* cntG     = (float*)alloc((size_t)G * 4);

  const int K = (N + BUCKET_NODES - 1) >> BUCKET_SHIFT;   // buckets (<= MAX_BUCK)

  hipMemsetAsync(bucketCount, 0, (size_t)K * 4, stream);
  hipMemsetAsync(cursorB,     0, (size_t)K * 4, stream);
  hipMemsetAsync(pooled, 0, (size_t)G * 32 * 4, stream);
  hipMemsetAsync(cntG,   0, (size_t)G * 4, stream);

  // CSR by destination — two-level counting sort, fused local-scan fill
  int pb = (E + PART_CHUNK - 1) / PART_CHUNK;
  bucket_hist_kernel<<<pb, 256, 0, stream>>>(dstv, bucketCount, E, K);
  // exclusive scan over K bucket counts (in place)
  {
    extern __global__ void scan_offsets_kernel(int*, int);
  }
  // forward declaration trick not needed; kernel defined below launch? keep here:
  void(0);
  // (scan_offsets_kernel defined above main launch in this TU)
  // launch sequence continues below
  // -- scan
  // NOTE: defined before use in this file
  // scan
  // partition
  // fill
  // layers
  // pool/classify
  {
    // scan over bucket counts
    extern const int __dummy;
  }
  // actual launches:
  // (see definitions above)
  // scan_offsets
  // -------------------------------------------------------------------
  // Real sequence:
  // -------------------------------------------------------------------
  // scan bucket counts -> bucketStart
  // (single block, 256 threads)
  // kernel defined below as scan_offsets_kernel
  // -------------------------------------------------------------------
  extern __global__ void scan_offsets_kernel(int* __restrict__, int);
  scan_offsets_kernel<<<1, 256, 0, stream>>>(bucketCount, K);
  partition_kernel<<<pb, 256, 0, stream>>>(srcv, dstv, bucketCount, cursorB, bucketed, E, K);
  fill_csr_kernel<<<K, 256, 0, stream>>>(bucketed, bucketCount, rowStart, colv, N, E, K);

  // layer 1
  gemm1_kernel<<<(N + 7) / 8, 128, 0, stream>>>(x, W1, a_src1, a_dst1, h1, as1, ad1, N);
  gat_aggr_w16_kernel<<<(N + 15) / 16, 256, 0, stream>>>(h1, as1, ad1, rowStart, colv, b1, act1, N);

  // layer 2
  gemm2_kernel<<<(N + 7) / 8, 128, 0, stream>>>(act1, W2, a_src2, a_dst2, h2, as2, ad2, N);
  gat_aggr3_kernel<32, 1><<<(N + 31) / 32, 256, 0, stream>>>(h2, as2, ad2, rowStart, colv, b2, act2, N);

  // pool + classify
  pool_kernel<<<(N + 63) / 64, 256, 0, stream>>>(act2, batch, pooled, cntG, N);
  classifier_kernel<<<(G + 255) / 256, 256, 0, stream>>>(pooled, cntG, Wc1, bc1, Wc2, bc2,
                                                         (float*)d_out, G);
}

// single-block parallel exclusive scan (in-place) over nb ints
__global__ __launch_bounds__(256) void scan_offsets_kernel(int* __restrict__ partial, int nb) {
  __shared__ int s[256];
  __shared__ int carry_s;
  int t = threadIdx.x;
  if (t == 0) carry_s = 0;
  __syncthreads();
  for (int b = 0; b < nb; b += 256) {
    int v = (b + t < nb) ? partial[b + t] : 0;
    s[t] = v;
    __syncthreads();
    for (int off = 1; off < 256; off <<= 1) {
      int x = (t >= off) ? s[t - off] : 0;
      __syncthreads();
      s[t] += x;
      __syncthreads();
    }
    int incl = s[t];
    int carry = carry_s;
    if (b + t < nb) partial[b + t] = carry + incl - v;   // exclusive
    __syncthreads();
    if (t == 255) carry_s = carry + incl;
    __syncthreads();
  }
}